// Round 11
// baseline (74.122 us; speedup 1.0000x reference)
//
#include <hip/hip_runtime.h>
#include <math.h>

#define NB 4096
#define ND 512
#define K2 1024
#define NT8 8  // K2 / 128 K-tiles

typedef __attribute__((ext_vector_type(4))) float f32x4;
typedef __attribute__((ext_vector_type(16))) float f32x16;

// ---------------------------------------------------------------------------
// Kernel 1: build A=[v_mean|v_sigma], B=[t_mean|t_sigma] in fp8 e4m3, written
// in MFMA FRAGMENT ORDER so the GEMM's LDS reads are conflict-free by
// construction:
//   A: [rb(32)][t(8)][g(4)][ks(8)][lane(64)=kh*32+r5][8B]   (131072 B / rb)
//   B: [rb(16)][t(8)][g(8)][ks(8)][lane(64)][8B]            (262144 B / rb)
// where element (row, k): g=row>>5 (within 128/256-row block), r5=row&31,
// t=k>>7, ks=(k>>4)&7, kh=(k>>3)&1, j=k&7.
// Also accumulates exact f32 row norms a_sq[i]=Σmean²+Σvar via atomicAdd
// (sq arrays are zeroed by hipMemsetAsync before this kernel).
// Blocks 0..255: A-side (rb=bid>>3, t=bid&7).
// Blocks 256..511: B-side (b=bid-256: rb=b>>4, t=(b&15)>>1, h=b&1).
// ---------------------------------------------------------------------------
__global__ __launch_bounds__(256) void prep_kernel(
    const float* __restrict__ v_mean, const float* __restrict__ v_var,
    const float* __restrict__ t_mean, const float* __restrict__ t_var,
    unsigned char* __restrict__ Afp, unsigned char* __restrict__ Bfp,
    float* __restrict__ a_sq, float* __restrict__ b_sq) {
  __shared__ __align__(16) unsigned char lfp[128 * 136];  // +8B row pad
  int bid = blockIdx.x;
  int tid = threadIdx.x;
  const float* src;
  unsigned char* dst;
  float* sq;
  int row0;
  bool isVar;
  if (bid < 256) {
    int rb = bid >> 3, t = bid & 7;
    row0 = rb * 128;
    isVar = t >= 4;
    src = (isVar ? v_var : v_mean) + (size_t)row0 * ND + (t & 3) * 128;
    dst = Afp + (size_t)rb * 131072 + t * 16384;
    sq = a_sq;
  } else {
    int b = bid - 256;
    int rb = b >> 4, rem = b & 15, t = rem >> 1, h = rem & 1;
    row0 = rb * 256 + h * 128;
    isVar = t >= 4;
    src = (isVar ? t_var : t_mean) + (size_t)row0 * ND + (t & 3) * 128;
    dst = Bfp + (size_t)rb * 262144 + t * 32768 + h * 16384;
    sq = b_sq;
  }
  // Phase 1: coalesced load 128 rows x 128 f32, convert fp8 -> LDS [r][136].
  // Each wave-instruction covers 2 full rows (coalesced 512B segments).
#pragma unroll
  for (int q = 0; q < 16; ++q) {
    int flat = q * 256 + tid;
    int row = flat >> 5, c4 = flat & 31;
    float4 v = *(const float4*)(src + row * ND + c4 * 4);
    float p;
    float4 w;
    if (isVar) {
      p = (v.x + v.y) + (v.z + v.w);
      w.x = sqrtf(v.x); w.y = sqrtf(v.y); w.z = sqrtf(v.z); w.w = sqrtf(v.w);
    } else {
      p = (v.x * v.x + v.y * v.y) + (v.z * v.z + v.w * v.w);
      w = v;
    }
    int p01 = __builtin_amdgcn_cvt_pk_fp8_f32(w.x, w.y, 0, false);
    int p23 = __builtin_amdgcn_cvt_pk_fp8_f32(w.z, w.w, 0, false);
    unsigned u = (unsigned)(p01 & 0xFFFF) | ((unsigned)(p23 & 0xFFFF) << 16);
    *(unsigned*)(lfp + row * 136 + c4 * 4) = u;
    // row is constant across each 32-lane group: reduce and one atomic/row.
#pragma unroll
    for (int o = 1; o <= 16; o <<= 1) p += __shfl_xor(p, o);
    if ((tid & 31) == 0) atomicAdd(sq + row0 + row, p);
  }
  __syncthreads();
  // Phase 2: write 64 B/thread of fragment-ordered output (coalesced).
  // o = tid*64 -> g=tid>>6, ks=(tid>>3)&7, kh=(tid>>2)&1, r5base=(tid&3)*8.
  {
    int g = tid >> 6, ks = (tid >> 3) & 7, kh = (tid >> 2) & 1;
    int r5b = (tid & 3) * 8;
    unsigned char* o = dst + tid * 64;
#pragma unroll
    for (int c = 0; c < 4; ++c) {
      int r0 = g * 32 + r5b + c * 2;
      unsigned long long lo =
          *(const unsigned long long*)(lfp + r0 * 136 + ks * 16 + kh * 8);
      unsigned long long hi =
          *(const unsigned long long*)(lfp + (r0 + 1) * 136 + ks * 16 + kh * 8);
      ulonglong2 v2;
      v2.x = lo;
      v2.y = hi;
      *(ulonglong2*)(o + c * 16) = v2;
    }
  }
}

// ---------------------------------------------------------------------------
// Kernel 2: 128x256-tile fp8 GEMM via NON-SCALED mfma_f32_32x32x16_fp8_fp8.
// R10 structure (proven spill-free: VGPR=64+AGPR acc, 2 blocks/CU TLP,
// single-buffered 48 KiB LDS) with the fragment-ordered operands:
//   staging  = linear 16B chunks (global offset == LDS offset within tile)
//   frag read = ds_read_b64 at g*4096 + ks*512 + lane*8  -> CONFLICT-FREE
//     (lane-linear stride-8: each 16-lane phase covers all 32 banks once).
// Fused online-LSE partials in the epilogue:
//   rowM/rowS[row][64]  ch = bn*4+wc    colM/colS[col][64]  ch = bm*2+wr
// ---------------------------------------------------------------------------
__global__ __launch_bounds__(512, 4) void gemm_fused_kernel(
    const unsigned char* __restrict__ Afp, const unsigned char* __restrict__ Bfp,
    const float* __restrict__ a_sq, const float* __restrict__ b_sq,
    const float* __restrict__ log_temp,
    float* __restrict__ rowM, float* __restrict__ rowS,
    float* __restrict__ colM, float* __restrict__ colS,
    float* __restrict__ diag) {
  __shared__ unsigned char ldsA[128 * 128];  // 16 KB, [g(4)][ks(8)][lane][8B]
  __shared__ unsigned char ldsB[256 * 128];  // 32 KB, [g(8)][ks(8)][lane][8B]
  int bid = blockIdx.x;
  // XCD-aware swizzle: 512 blocks, 8 XCDs -> 64 contiguous per XCD (bijective).
  int swz = (bid & 7) * 64 + (bid >> 3);
  int bm = swz >> 4, bn = swz & 15;  // 32 x 16 grid
  int brow = bm * 128, bcol = bn * 256;
  int tid = threadIdx.x;
  int lane = tid & 63, wid = tid >> 6;
  int wr = wid >> 2, wc = wid & 3;  // 2x4 wave grid, wave = 64x64
  int l31 = lane & 31, kh = lane >> 5;

  const unsigned char* Ablk = Afp + (size_t)bm * 131072;
  const unsigned char* Bblk = Bfp + (size_t)bn * 262144;

#define STAGE(T)                                                               \
  {                                                                            \
    _Pragma("unroll") for (int s = 0; s < 2; ++s)                              \
        __builtin_amdgcn_global_load_lds(                                      \
            (const __attribute__((address_space(1))) unsigned int*)(Ablk +     \
                (unsigned)(T) * 16384 + s * 8192 + tid * 16),                  \
            (__attribute__((address_space(3))) unsigned int*)(ldsA + s * 8192 +\
                tid * 16),                                                     \
            16, 0, 0);                                                         \
    _Pragma("unroll") for (int s = 0; s < 4; ++s)                              \
        __builtin_amdgcn_global_load_lds(                                      \
            (const __attribute__((address_space(1))) unsigned int*)(Bblk +     \
                (unsigned)(T) * 32768 + s * 8192 + tid * 16),                  \
            (__attribute__((address_space(3))) unsigned int*)(ldsB + s * 8192 +\
                tid * 16),                                                     \
            16, 0, 0);                                                         \
  }

  // Fragment bases: lane-linear, conflict-free. ks*512 folds into ds offset.
  unsigned aB[2], bB[2];
#pragma unroll
  for (int mi = 0; mi < 2; ++mi) aB[mi] = (unsigned)(wr * 2 + mi) * 4096 + lane * 8;
#pragma unroll
  for (int ni = 0; ni < 2; ++ni) bB[ni] = (unsigned)(wc * 2 + ni) * 4096 + lane * 8;

  f32x16 acc[2][2] = {};

  STAGE(0);
  asm volatile("s_waitcnt vmcnt(0)" ::: "memory");
  __builtin_amdgcn_s_barrier();

  for (int t = 0; t < NT8; ++t) {
    long a0, a1, b0, b1;
    // ksteps 0..6: read 4 x b64 (8 regs) + 4 MFMA each.
#pragma unroll
    for (int ks = 0; ks < 7; ++ks) {
      unsigned ko = (unsigned)ks * 512;
      a0 = *(const long*)(ldsA + aB[0] + ko);
      a1 = *(const long*)(ldsA + aB[1] + ko);
      b0 = *(const long*)(ldsB + bB[0] + ko);
      b1 = *(const long*)(ldsB + bB[1] + ko);
      __builtin_amdgcn_s_setprio(1);
      acc[0][0] = __builtin_amdgcn_mfma_f32_32x32x16_fp8_fp8(a0, b0, acc[0][0], 0, 0, 0);
      acc[0][1] = __builtin_amdgcn_mfma_f32_32x32x16_fp8_fp8(a0, b1, acc[0][1], 0, 0, 0);
      acc[1][0] = __builtin_amdgcn_mfma_f32_32x32x16_fp8_fp8(a1, b0, acc[1][0], 0, 0, 0);
      acc[1][1] = __builtin_amdgcn_mfma_f32_32x32x16_fp8_fp8(a1, b1, acc[1][1], 0, 0, 0);
      __builtin_amdgcn_s_setprio(0);
    }
    // kstep 7: read, drain LDS reads, barrier -> tile fully consumed.
    a0 = *(const long*)(ldsA + aB[0] + 3584);
    a1 = *(const long*)(ldsA + aB[1] + 3584);
    b0 = *(const long*)(ldsB + bB[0] + 3584);
    b1 = *(const long*)(ldsB + bB[1] + 3584);
    asm volatile("s_waitcnt lgkmcnt(0)" ::: "memory");
    __builtin_amdgcn_s_barrier();
    // Restage same buffer for tile t+1 (async; lands before next barrier).
    if (t + 1 < NT8) STAGE(t + 1);
    // kstep 7 MFMA on registers, overlapping the stage flight time.
    __builtin_amdgcn_s_setprio(1);
    acc[0][0] = __builtin_amdgcn_mfma_f32_32x32x16_fp8_fp8(a0, b0, acc[0][0], 0, 0, 0);
    acc[0][1] = __builtin_amdgcn_mfma_f32_32x32x16_fp8_fp8(a0, b1, acc[0][1], 0, 0, 0);
    acc[1][0] = __builtin_amdgcn_mfma_f32_32x32x16_fp8_fp8(a1, b0, acc[1][0], 0, 0, 0);
    acc[1][1] = __builtin_amdgcn_mfma_f32_32x32x16_fp8_fp8(a1, b1, acc[1][1], 0, 0, 0);
    __builtin_amdgcn_s_setprio(0);
    asm volatile("s_waitcnt vmcnt(0)" ::: "memory");
    __builtin_amdgcn_s_barrier();
  }

  // ---- epilogue: logits in-place, diag, fused online-LSE partials ----
  // 32x32 C/D layout (m74/m101, dtype-independent):
  //   col = lane&31, row = (reg&3) + 8*(reg>>2) + 4*(lane>>5).
  float temp = fminf(expf(log_temp[0]), 100.0f);
#pragma unroll
  for (int mi = 0; mi < 2; ++mi) {
#pragma unroll
    for (int reg = 0; reg < 16; ++reg) {
      int rl = wr * 64 + mi * 32 + (reg & 3) + 8 * (reg >> 2) + 4 * kh;
      float asq = a_sq[brow + rl];
#pragma unroll
      for (int ni = 0; ni < 2; ++ni) {
        float bsq = b_sq[bcol + wc * 64 + ni * 32 + l31];
        acc[mi][ni][reg] = -temp * (asq + bsq - 2.0f * acc[mi][ni][reg]);
      }
    }
  }
  // Diagonal: block contains global diag iff (bm>>1)==bn.
  if ((bm >> 1) == bn) {
#pragma unroll
    for (int mi = 0; mi < 2; ++mi)
#pragma unroll
      for (int ni = 0; ni < 2; ++ni)
#pragma unroll
        for (int reg = 0; reg < 16; ++reg) {
          int rl = wr * 64 + mi * 32 + (reg & 3) + 8 * (reg >> 2) + 4 * kh;
          int cl = wc * 64 + ni * 32 + l31;
          if (brow + rl == bcol + cl) diag[brow + rl] = acc[mi][ni][reg];
        }
  }
  // Row partials: per (mi,reg): 2 in-lane + reduce across 32 cols (l31).
#pragma unroll
  for (int mi = 0; mi < 2; ++mi) {
#pragma unroll
    for (int reg = 0; reg < 16; ++reg) {
      float mx = fmaxf(acc[mi][0][reg], acc[mi][1][reg]);
#pragma unroll
      for (int o = 1; o < 32; o <<= 1) mx = fmaxf(mx, __shfl_xor(mx, o));
      float s = __expf(acc[mi][0][reg] - mx) + __expf(acc[mi][1][reg] - mx);
#pragma unroll
      for (int o = 1; o < 32; o <<= 1) s += __shfl_xor(s, o);
      if (l31 == 0) {
        int row = brow + wr * 64 + mi * 32 + (reg & 3) + 8 * (reg >> 2) + 4 * kh;
        int ch = bn * 4 + wc;
        rowM[(size_t)row * 64 + ch] = mx;
        rowS[(size_t)row * 64 + ch] = s;
      }
    }
  }
  // Col partials: per ni: 32 in-lane (mi,reg) + merge kh halves (xor 32).
#pragma unroll
  for (int ni = 0; ni < 2; ++ni) {
    float mx = -INFINITY;
#pragma unroll
    for (int mi = 0; mi < 2; ++mi)
#pragma unroll
      for (int reg = 0; reg < 16; ++reg) mx = fmaxf(mx, acc[mi][ni][reg]);
    mx = fmaxf(mx, __shfl_xor(mx, 32));
    float s = 0.f;
#pragma unroll
    for (int mi = 0; mi < 2; ++mi)
#pragma unroll
      for (int reg = 0; reg < 16; ++reg) s += __expf(acc[mi][ni][reg] - mx);
    s += __shfl_xor(s, 32);
    if (kh == 0) {
      int col = bcol + wc * 64 + ni * 32 + l31;
      int ch = bm * 2 + wr;
      colM[(size_t)col * 64 + ch] = mx;
      colS[(size_t)col * 64 + ch] = s;
    }
  }
}

// ---------------------------------------------------------------------------
// Kernel 3: combine 64 chunk-partials per row/col -> (lse - diag).
// ---------------------------------------------------------------------------
__global__ __launch_bounds__(256) void combine_kernel(
    const float* __restrict__ rowM, const float* __restrict__ rowS,
    const float* __restrict__ colM, const float* __restrict__ colS,
    const float* __restrict__ diag, float* __restrict__ hrow,
    float* __restrict__ hcol) {
  int b = blockIdx.x;
  int t = threadIdx.x;
  int wave = t >> 6, lane = t & 63;
  int isCol = b >> 10;
  int idx = (b & 1023) * 4 + wave;
  const float* PM = isCol ? colM : rowM;
  const float* PS = isCol ? colS : rowS;
  float M = PM[(size_t)idx * 64 + lane];
  float S = PS[(size_t)idx * 64 + lane];
#pragma unroll
  for (int o = 1; o < 64; o <<= 1) {
    float M2 = __shfl_xor(M, o), S2 = __shfl_xor(S, o);
    float nM = fmaxf(M, M2);
    S = S * __expf(M - nM) + S2 * __expf(M2 - nM);
    M = nM;
  }
  if (lane == 0) {
    float v = M + logf(S) - diag[idx];
    (isCol ? hcol : hrow)[idx] = v;
  }
}

// Kernel 4: final mean in f64: 0.5*(mean(hrow) + mean(hcol)).
__global__ __launch_bounds__(256) void final_kernel(
    const float* __restrict__ hrow, const float* __restrict__ hcol,
    float* __restrict__ out) {
  int t = threadIdx.x;
  double a = 0.0;
  for (int i = t; i < NB; i += 256) {
    a += 0.5 * ((double)hrow[i] + (double)hcol[i]);
  }
#pragma unroll
  for (int o = 32; o > 0; o >>= 1) a += __shfl_xor(a, o);
  __shared__ double sd[4];
  if ((t & 63) == 0) sd[t >> 6] = a;
  __syncthreads();
  if (t == 0) out[0] = (float)(((sd[0] + sd[1]) + (sd[2] + sd[3])) / (double)NB);
}

extern "C" void kernel_launch(void* const* d_in, const int* in_sizes, int n_in,
                              void* d_out, int out_size, void* d_ws, size_t ws_size,
                              hipStream_t stream) {
  const float* v_mean = (const float*)d_in[0];
  const float* v_var = (const float*)d_in[1];
  const float* t_mean = (const float*)d_in[2];
  const float* t_var = (const float*)d_in[3];
  const float* log_temp = (const float*)d_in[4];
  float* out = (float*)d_out;

  char* ws = (char*)d_ws;
  unsigned char* Afp = (unsigned char*)ws;                       // 4 MiB
  unsigned char* Bfp = (unsigned char*)(ws + 4194304);           // 4 MiB
  float* rowM = (float*)(ws + 8388608);                          // 1 MiB each
  float* rowS = rowM + (size_t)NB * 64;
  float* colM = rowS + (size_t)NB * 64;
  float* colS = colM + (size_t)NB * 64;
  float* diag = colS + (size_t)NB * 64;                          // 16 KiB each
  float* hrow = diag + NB;
  float* hcol = hrow + NB;
  float* a_sq = hcol + NB;
  float* b_sq = a_sq + NB;

  // Zero the atomic accumulators (a_sq, b_sq are contiguous).
  hipMemsetAsync(a_sq, 0, 2 * (size_t)NB * sizeof(float), stream);
  prep_kernel<<<512, 256, 0, stream>>>(v_mean, v_var, t_mean, t_var, Afp, Bfp, a_sq, b_sq);
  gemm_fused_kernel<<<512, 512, 0, stream>>>(Afp, Bfp, a_sq, b_sq, log_temp,
                                             rowM, rowS, colM, colS, diag);
  combine_kernel<<<2048, 256, 0, stream>>>(rowM, rowS, colM, colS, diag, hrow, hcol);
  final_kernel<<<1, 256, 0, stream>>>(hrow, hcol, out);
}

// Round 12
// 68.997 us; speedup vs baseline: 1.0743x; 1.0743x over previous
//
#include <hip/hip_runtime.h>
#include <math.h>

#define NB 4096
#define ND 512
#define K2 1024
#define NT16 16  // K2 / 64 K-tiles

typedef __attribute__((ext_vector_type(16))) float f32x16;

// ---------------------------------------------------------------------------
// Kernel 1: build A=[v_mean|v_sigma] (4096x1024 fp8 e4m3) and B likewise, in
// MFMA FRAGMENT ORDER:
//   A: [rb(32)][t(8)][g(4)][ks8(8)][lane(64)=kh*32+r5][8B]   (131072 B / rb)
//   B: [rb(16)][t(8)][g(8)][ks8(8)][lane(64)][8B]            (262144 B / rb)
// element (row,k): g=(row>>5)&3 (A) or &7 (B), r5=row&31; t=k>>7,
// ks8=(k>>4)&7, kh=(k>>3)&1, j=k&7.
// 2048 blocks (8 waves of work each -> 8/CU), each handling one (rb,t,g):
// 32 rows x 128 cols. Row norms a_sq[i]=Σmean²+Σvar via atomicAdd (arrays
// zeroed by hipMemsetAsync).
// Blocks 0..1023: A (rb=bid>>5, t=(bid>>2)&7, g=bid&3).
// Blocks 1024..2047: B (b=bid-1024: rb=b>>6, t=(b>>3)&7, g=b&7).
// ---------------------------------------------------------------------------
__global__ __launch_bounds__(256) void prep_kernel(
    const float* __restrict__ v_mean, const float* __restrict__ v_var,
    const float* __restrict__ t_mean, const float* __restrict__ t_var,
    unsigned char* __restrict__ Afp, unsigned char* __restrict__ Bfp,
    float* __restrict__ a_sq, float* __restrict__ b_sq) {
  __shared__ __align__(8) unsigned char lfp[32 * 132];  // 132B row stride
  int bid = blockIdx.x;
  int tid = threadIdx.x;
  const float* src;
  unsigned char* dst;
  float* sq;
  int row0;
  bool isVar;
  if (bid < 1024) {
    int rb = bid >> 5, t = (bid >> 2) & 7, g = bid & 3;
    row0 = rb * 128 + g * 32;
    isVar = t >= 4;
    src = (isVar ? v_var : v_mean) + (size_t)row0 * ND + (t & 3) * 128;
    dst = Afp + (size_t)rb * 131072 + t * 16384 + g * 4096;
    sq = a_sq;
  } else {
    int b = bid - 1024;
    int rb = b >> 6, t = (b >> 3) & 7, g = b & 7;
    row0 = rb * 256 + g * 32;
    isVar = t >= 4;
    src = (isVar ? t_var : t_mean) + (size_t)row0 * ND + (t & 3) * 128;
    dst = Bfp + (size_t)rb * 262144 + t * 32768 + g * 4096;
    sq = b_sq;
  }
  // Phase 1: coalesced read 32x128 f32 (512B per 32-lane group), fp8->LDS,
  // per-row norm partial via 32-lane shuffle reduce + one atomic per row.
#pragma unroll
  for (int q = 0; q < 4; ++q) {
    int flat = q * 256 + tid;
    int row = flat >> 5, col4 = flat & 31;
    float4 v = *(const float4*)(src + row * ND + col4 * 4);
    float p;
    float4 w;
    if (isVar) {
      p = (v.x + v.y) + (v.z + v.w);
      w.x = sqrtf(v.x); w.y = sqrtf(v.y); w.z = sqrtf(v.z); w.w = sqrtf(v.w);
    } else {
      p = (v.x * v.x + v.y * v.y) + (v.z * v.z + v.w * v.w);
      w = v;
    }
    int p01 = __builtin_amdgcn_cvt_pk_fp8_f32(w.x, w.y, 0, false);
    int p23 = __builtin_amdgcn_cvt_pk_fp8_f32(w.z, w.w, 0, false);
    unsigned u = (unsigned)(p01 & 0xFFFF) | ((unsigned)(p23 & 0xFFFF) << 16);
    *(unsigned*)(lfp + row * 132 + col4 * 4) = u;
#pragma unroll
    for (int o = 1; o <= 16; o <<= 1) p += __shfl_xor(p, o);
    if ((tid & 31) == 0) atomicAdd(sq + row0 + row, p);
  }
  __syncthreads();
  // Phase 2: fragment-order writes. Wave wv handles ks8 = 2wv, 2wv+1; lane l
  // reads lfp[l&31][ks8*16 + (l>>5)*8] (8B; 2-way bank alias = free) and
  // stores at dst + ks8*512 + l*8 (512B coalesced per wave-instruction).
  {
    int wv = tid >> 6, l = tid & 63;
    int r5 = l & 31, kh = l >> 5;
#pragma unroll
    for (int cc = 0; cc < 2; ++cc) {
      int ks8 = wv * 2 + cc;
      unsigned long long d =
          *(const unsigned long long*)(lfp + r5 * 132 + ks8 * 16 + kh * 8);
      *(unsigned long long*)(dst + ks8 * 512 + l * 8) = d;
    }
  }
}

// ---------------------------------------------------------------------------
// Kernel 2: 128x256-tile fp8 GEMM via mfma_f32_32x32x16_fp8_fp8, BK=64,
// DOUBLE-buffered LDS (2 x 24 KB = 48 KB -> still 2 blocks/CU TLP).
// Per tile: issue STAGE(t+1 -> other buf) FIRST (whole tile's compute hides
// its latency), 4 ksteps of {4 conflict-free b64 reads + 4 MFMA}, then one
// lgkmcnt(0)+vmcnt(0)+barrier. One barrier per tile, zero stage exposure.
// Fragment-ordered operands: staging is linear 16B chunks; frag read =
// g*2048 + ks*512 + lane*8 (lane-linear stride-8, conflict-free).
// Fused online-LSE partials in the epilogue:
//   rowM/rowS[row][64]  ch = bn*4+wc    colM/colS[col][64]  ch = bm*2+wr
// ---------------------------------------------------------------------------
__global__ __launch_bounds__(512, 4) void gemm_fused_kernel(
    const unsigned char* __restrict__ Afp, const unsigned char* __restrict__ Bfp,
    const float* __restrict__ a_sq, const float* __restrict__ b_sq,
    const float* __restrict__ log_temp,
    float* __restrict__ rowM, float* __restrict__ rowS,
    float* __restrict__ colM, float* __restrict__ colS,
    float* __restrict__ diag) {
  __shared__ unsigned char ldsA[2][8192];   // [g(4)][ks(4)][lane][8B]
  __shared__ unsigned char ldsB[2][16384];  // [g(8)][ks(4)][lane][8B]
  int bid = blockIdx.x;
  // XCD-aware swizzle: 512 blocks, 8 XCDs -> 64 contiguous per XCD (bijective).
  int swz = (bid & 7) * 64 + (bid >> 3);
  int bm = swz >> 4, bn = swz & 15;  // 32 x 16 grid
  int brow = bm * 128, bcol = bn * 256;
  int tid = threadIdx.x;
  int lane = tid & 63, wid = tid >> 6;
  int wr = wid >> 2, wc = wid & 3;  // 2x4 wave grid, wave = 64x64
  int l31 = lane & 31, kh = lane >> 5;

  const unsigned char* Ablk = Afp + (size_t)bm * 131072;
  const unsigned char* Bblk = Bfp + (size_t)bn * 262144;

  // Staging decomposition: 3 x 16B loads/thread (A 8 KB, B 16 KB per tile).
  int gA = tid >> 7;             // 0..3
  unsigned offA = (unsigned)(tid & 127) * 16;

#define STAGE(TT, C)                                                           \
  {                                                                            \
    unsigned t16 = (unsigned)((TT) >> 1) * 16384u;                             \
    unsigned t32 = (unsigned)((TT) >> 1) * 32768u;                             \
    unsigned hf = (unsigned)((TT) & 1) * 2048u;                                \
    __builtin_amdgcn_global_load_lds(                                          \
        (const __attribute__((address_space(1))) unsigned int*)(Ablk + t16 +   \
            gA * 4096 + hf + offA),                                            \
        (__attribute__((address_space(3))) unsigned int*)(&ldsA[C][0] +        \
            gA * 2048 + offA),                                                 \
        16, 0, 0);                                                             \
    _Pragma("unroll") for (int cc = 0; cc < 2; ++cc)                           \
        __builtin_amdgcn_global_load_lds(                                      \
            (const __attribute__((address_space(1))) unsigned int*)(Bblk +     \
                t32 + (cc * 4 + gA) * 4096 + hf + offA),                       \
            (__attribute__((address_space(3))) unsigned int*)(&ldsB[C][0] +    \
                (cc * 4 + gA) * 2048 + offA),                                  \
            16, 0, 0);                                                         \
  }

  // Fragment bases (byte offsets): lane-linear, conflict-free.
  unsigned aB0 = (unsigned)(wr * 2 + 0) * 2048 + lane * 8;
  unsigned aB1 = (unsigned)(wr * 2 + 1) * 2048 + lane * 8;
  unsigned bB0 = (unsigned)(wc * 2 + 0) * 2048 + lane * 8;
  unsigned bB1 = (unsigned)(wc * 2 + 1) * 2048 + lane * 8;

  f32x16 acc[2][2] = {};

  STAGE(0, 0);
  asm volatile("s_waitcnt vmcnt(0)" ::: "memory");
  __builtin_amdgcn_s_barrier();

  for (int tt = 0; tt < NT16; ++tt) {
    const int c = tt & 1;
    const unsigned char* bufa = &ldsA[c][0];
    const unsigned char* bufb = &ldsB[c][0];
    if (tt + 1 < NT16) STAGE(tt + 1, c ^ 1);
#pragma unroll
    for (int ks = 0; ks < 4; ++ks) {
      unsigned ko = (unsigned)ks * 512;
      long a0 = *(const long*)(bufa + aB0 + ko);
      long a1 = *(const long*)(bufa + aB1 + ko);
      long b0 = *(const long*)(bufb + bB0 + ko);
      long b1 = *(const long*)(bufb + bB1 + ko);
      __builtin_amdgcn_s_setprio(1);
      acc[0][0] = __builtin_amdgcn_mfma_f32_32x32x16_fp8_fp8(a0, b0, acc[0][0], 0, 0, 0);
      acc[0][1] = __builtin_amdgcn_mfma_f32_32x32x16_fp8_fp8(a0, b1, acc[0][1], 0, 0, 0);
      acc[1][0] = __builtin_amdgcn_mfma_f32_32x32x16_fp8_fp8(a1, b0, acc[1][0], 0, 0, 0);
      acc[1][1] = __builtin_amdgcn_mfma_f32_32x32x16_fp8_fp8(a1, b1, acc[1][1], 0, 0, 0);
      __builtin_amdgcn_s_setprio(0);
    }
    // Own reads returned (lgkm) + next tile's stage landed (vm, fully covered
    // by this tile's compute) -> one barrier per tile.
    asm volatile("s_waitcnt lgkmcnt(0)" ::: "memory");
    asm volatile("s_waitcnt vmcnt(0)" ::: "memory");
    __builtin_amdgcn_s_barrier();
  }

  // ---- epilogue: logits in-place, diag, fused online-LSE partials ----
  // 32x32 C/D layout (m74/m101, dtype-independent):
  //   col = lane&31, row = (reg&3) + 8*(reg>>2) + 4*(lane>>5).
  float temp = fminf(expf(log_temp[0]), 100.0f);
#pragma unroll
  for (int mi = 0; mi < 2; ++mi) {
#pragma unroll
    for (int reg = 0; reg < 16; ++reg) {
      int rl = wr * 64 + mi * 32 + (reg & 3) + 8 * (reg >> 2) + 4 * kh;
      float asq = a_sq[brow + rl];
#pragma unroll
      for (int ni = 0; ni < 2; ++ni) {
        float bsq = b_sq[bcol + wc * 64 + ni * 32 + l31];
        acc[mi][ni][reg] = -temp * (asq + bsq - 2.0f * acc[mi][ni][reg]);
      }
    }
  }
  // Diagonal: block contains global diag iff (bm>>1)==bn.
  if ((bm >> 1) == bn) {
#pragma unroll
    for (int mi = 0; mi < 2; ++mi)
#pragma unroll
      for (int ni = 0; ni < 2; ++ni)
#pragma unroll
        for (int reg = 0; reg < 16; ++reg) {
          int rl = wr * 64 + mi * 32 + (reg & 3) + 8 * (reg >> 2) + 4 * kh;
          int cl = wc * 64 + ni * 32 + l31;
          if (brow + rl == bcol + cl) diag[brow + rl] = acc[mi][ni][reg];
        }
  }
  // Row partials: per (mi,reg): 2 in-lane + reduce across 32 cols (l31).
#pragma unroll
  for (int mi = 0; mi < 2; ++mi) {
#pragma unroll
    for (int reg = 0; reg < 16; ++reg) {
      float mx = fmaxf(acc[mi][0][reg], acc[mi][1][reg]);
#pragma unroll
      for (int o = 1; o < 32; o <<= 1) mx = fmaxf(mx, __shfl_xor(mx, o));
      float s = __expf(acc[mi][0][reg] - mx) + __expf(acc[mi][1][reg] - mx);
#pragma unroll
      for (int o = 1; o < 32; o <<= 1) s += __shfl_xor(s, o);
      if (l31 == 0) {
        int row = brow + wr * 64 + mi * 32 + (reg & 3) + 8 * (reg >> 2) + 4 * kh;
        int ch = bn * 4 + wc;
        rowM[(size_t)row * 64 + ch] = mx;
        rowS[(size_t)row * 64 + ch] = s;
      }
    }
  }
  // Col partials: per ni: 32 in-lane (mi,reg) + merge kh halves (xor 32).
#pragma unroll
  for (int ni = 0; ni < 2; ++ni) {
    float mx = -INFINITY;
#pragma unroll
    for (int mi = 0; mi < 2; ++mi)
#pragma unroll
      for (int reg = 0; reg < 16; ++reg) mx = fmaxf(mx, acc[mi][ni][reg]);
    mx = fmaxf(mx, __shfl_xor(mx, 32));
    float s = 0.f;
#pragma unroll
    for (int mi = 0; mi < 2; ++mi)
#pragma unroll
      for (int reg = 0; reg < 16; ++reg) s += __expf(acc[mi][ni][reg] - mx);
    s += __shfl_xor(s, 32);
    if (kh == 0) {
      int col = bcol + wc * 64 + ni * 32 + l31;
      int ch = bm * 2 + wr;
      colM[(size_t)col * 64 + ch] = mx;
      colS[(size_t)col * 64 + ch] = s;
    }
  }
}

// ---------------------------------------------------------------------------
// Kernel 3: combine 64 chunk-partials per row/col -> (lse - diag).
// ---------------------------------------------------------------------------
__global__ __launch_bounds__(256) void combine_kernel(
    const float* __restrict__ rowM, const float* __restrict__ rowS,
    const float* __restrict__ colM, const float* __restrict__ colS,
    const float* __restrict__ diag, float* __restrict__ hrow,
    float* __restrict__ hcol) {
  int b = blockIdx.x;
  int t = threadIdx.x;
  int wave = t >> 6, lane = t & 63;
  int isCol = b >> 10;
  int idx = (b & 1023) * 4 + wave;
  const float* PM = isCol ? colM : rowM;
  const float* PS = isCol ? colS : rowS;
  float M = PM[(size_t)idx * 64 + lane];
  float S = PS[(size_t)idx * 64 + lane];
#pragma unroll
  for (int o = 1; o < 64; o <<= 1) {
    float M2 = __shfl_xor(M, o), S2 = __shfl_xor(S, o);
    float nM = fmaxf(M, M2);
    S = S * __expf(M - nM) + S2 * __expf(M2 - nM);
    M = nM;
  }
  if (lane == 0) {
    float v = M + logf(S) - diag[idx];
    (isCol ? hcol : hrow)[idx] = v;
  }
}

// Kernel 4: final mean in f64: 0.5*(mean(hrow) + mean(hcol)).
__global__ __launch_bounds__(256) void final_kernel(
    const float* __restrict__ hrow, const float* __restrict__ hcol,
    float* __restrict__ out) {
  int t = threadIdx.x;
  double a = 0.0;
  for (int i = t; i < NB; i += 256) {
    a += 0.5 * ((double)hrow[i] + (double)hcol[i]);
  }
#pragma unroll
  for (int o = 32; o > 0; o >>= 1) a += __shfl_xor(a, o);
  __shared__ double sd[4];
  if ((t & 63) == 0) sd[t >> 6] = a;
  __syncthreads();
  if (t == 0) out[0] = (float)(((sd[0] + sd[1]) + (sd[2] + sd[3])) / (double)NB);
}

extern "C" void kernel_launch(void* const* d_in, const int* in_sizes, int n_in,
                              void* d_out, int out_size, void* d_ws, size_t ws_size,
                              hipStream_t stream) {
  const float* v_mean = (const float*)d_in[0];
  const float* v_var = (const float*)d_in[1];
  const float* t_mean = (const float*)d_in[2];
  const float* t_var = (const float*)d_in[3];
  const float* log_temp = (const float*)d_in[4];
  float* out = (float*)d_out;

  char* ws = (char*)d_ws;
  unsigned char* Afp = (unsigned char*)ws;                       // 4 MiB
  unsigned char* Bfp = (unsigned char*)(ws + 4194304);           // 4 MiB
  float* rowM = (float*)(ws + 8388608);                          // 1 MiB each
  float* rowS = rowM + (size_t)NB * 64;
  float* colM = rowS + (size_t)NB * 64;
  float* colS = colM + (size_t)NB * 64;
  float* diag = colS + (size_t)NB * 64;                          // 16 KiB each
  float* hrow = diag + NB;
  float* hcol = hrow + NB;
  float* a_sq = hcol + NB;
  float* b_sq = a_sq + NB;

  // Zero the atomic accumulators (a_sq, b_sq contiguous).
  hipMemsetAsync(a_sq, 0, 2 * (size_t)NB * sizeof(float), stream);
  prep_kernel<<<2048, 256, 0, stream>>>(v_mean, v_var, t_mean, t_var, Afp, Bfp, a_sq, b_sq);
  gemm_fused_kernel<<<512, 512, 0, stream>>>(Afp, Bfp, a_sq, b_sq, log_temp,
                                             rowM, rowS, colM, colS, diag);
  combine_kernel<<<2048, 256, 0, stream>>>(rowM, rowS, colM, colS, diag, hrow, hcol);
  final_kernel<<<1, 256, 0, stream>>>(hrow, hcol, out);
}